// Round 6
// baseline (856.608 us; speedup 1.0000x reference)
//
#include <hip/hip_runtime.h>

#define B_    256
#define T_    2048
#define F_    37
#define TF    111   // 3F
#define U_    32
#define TU    96    // 3U
#define D_    16

#define KP    128   // padded K for MFMA
#define XSTR  136   // LDS row stride in bf16 (272 B)
#define MTILE 128   // timesteps per tile
#define TPB   4     // tiles per block (xz kernel)

#define L2E 1.4426950408889634f

typedef __attribute__((ext_vector_type(8))) short short8;
typedef __attribute__((ext_vector_type(4))) float f32x4;
typedef __attribute__((ext_vector_type(2))) float f32x2;

__device__ __forceinline__ float fast_exp2(float x) {
    float r; asm("v_exp_f32 %0, %1" : "=v"(r) : "v"(x)); return r;
}
__device__ __forceinline__ float fast_rcp(float x) {
    float r; asm("v_rcp_f32 %0, %1" : "=v"(r) : "v"(x)); return r;
}
__device__ __forceinline__ float sigmoid_fast(float x) {
    return fast_rcp(1.f + fast_exp2(-L2E * x));
}
__device__ __forceinline__ float rdlane(float v, int k) {
    return __uint_as_float(__builtin_amdgcn_readlane(__float_as_uint(v), k));
}
// every lane gets its cross-32 partner's value (hedge: partner = p0+p1-own)
__device__ __forceinline__ float swap_half(float x) {
    unsigned xi = __float_as_uint(x);
    auto p = __builtin_amdgcn_permlane32_swap(xi, xi, false, false);
    float f0 = __uint_as_float(p[0]);
    float f1 = __uint_as_float(p[1]);
    return (f0 + f1) - x;
}
__device__ __forceinline__ float bf2f(unsigned short u) {
    return __uint_as_float(((unsigned)u) << 16);
}
__device__ __forceinline__ unsigned short f2bf_rne(float x) {
    unsigned u = __float_as_uint(x);
    return (unsigned short)((u + 0x7FFFu + ((u >> 16) & 1u)) >> 16);
}
__device__ __forceinline__ unsigned pk_bf16(float a, float b) {
    unsigned u;
    asm("v_cvt_pk_bf16_f32 %0, %1, %2" : "=v"(u) : "v"(a), "v"(b));
    return u;
}
// byte-select: dst.b[i] = sel.b[i]<4 ? s1.byte(sel) : s0.byte(sel-4)
__device__ __forceinline__ unsigned perm_b32(unsigned s0, unsigned s1, unsigned sel) {
    unsigned d;
    asm("v_perm_b32 %0, %1, %2, %3" : "=v"(d) : "v"(s0), "v"(s1), "v"(sel));
    return d;
}

typedef union { unsigned u[4]; short8 v; } frag_u;

// ============================================================================
// Kernel 1: xz[b][t][0:96] = x[b,t,:] @ K + b_in (bf16 out), via MFMA.
// Tiles with t0 >= lengths[b] are skipped (validated rounds 2-5).
// ============================================================================
__global__ __launch_bounds__(256, 2) void gru_xz4_kernel(
    const float* __restrict__ dt,
    const float* __restrict__ values,
    const int*   __restrict__ meas,
    const float* __restrict__ kern,
    const float* __restrict__ bias,
    const int*   __restrict__ lengths,
    unsigned short* __restrict__ xz)
{
    __shared__ unsigned short sX[MTILE][XSTR];   // 34816 B
    __shared__ unsigned short sKT[TU][XSTR];     // 26112 B

    const int tid  = threadIdx.x;
    const int wave = tid >> 6;
    const int lane = tid & 63;
    const int lr   = lane & 15;          // A-row / B-col / D-col
    const int lk   = (lane >> 4) * 8;    // k offset within frag

    for (int idx = tid; idx < TU * (KP / 2); idx += 256) {
        int j = idx >> 6, kp = idx & 63;
        int k0 = 2 * kp, k1 = k0 + 1;
        float v0 = (k0 < TF) ? kern[k0 * TU + j] : 0.f;
        float v1 = (k1 < TF) ? kern[k1 * TU + j] : 0.f;
        *(unsigned*)&sKT[j][2 * kp] = pk_bf16(v0, v1);
    }
    __syncthreads();

    float bi[6];
    #pragma unroll
    for (int n = 0; n < 6; ++n) bi[n] = bias[n * 16 + lr];
    short8 bfr[6][4];
    #pragma unroll
    for (int n = 0; n < 6; ++n)
        #pragma unroll
        for (int kc = 0; kc < 4; ++kc)
            bfr[n][kc] = *(const short8*)&sKT[n * 16 + lr][kc * 32 + lk];

    for (int tt = 0; tt < TPB; ++tt) {
        const int tile = blockIdx.x * TPB + tt;
        const int b    = tile >> 4;
        const int t0   = (tile & 15) * MTILE;

        // uniform per block-iteration: all threads take the same path, so the
        // barrier pairing below stays consistent.
        if (t0 >= lengths[b]) continue;

        __syncthreads();

        for (int i = tid; i < MTILE * F_; i += 256) {
            int t = i / F_, f = i - t * F_;
            size_t g = ((size_t)b * T_ + (t0 + t)) * F_ + f;
            sX[t][f] = f2bf_rne(values[g]);
        }
        for (int i = tid; i < MTILE * F_; i += 256) {
            int t = i / F_, f = i - t * F_;
            size_t g = ((size_t)b * T_ + (t0 + t)) * F_ + f;
            sX[t][F_ + f] = meas[g] ? (unsigned short)0x3F80 : (unsigned short)0;
        }
        for (int i = tid; i < MTILE * F_; i += 256) {
            int t = i / F_, f = i - t * F_;
            size_t g = ((size_t)b * T_ + (t0 + t)) * F_ + f;
            sX[t][2 * F_ + f] = f2bf_rne(dt[g]);
        }
        for (int i = tid; i < MTILE * (KP - TF); i += 256) {
            int t = i / (KP - TF), p = i - t * (KP - TF);
            sX[t][TF + p] = 0;
        }
        __syncthreads();

        f32x4 acc[2][6];
        #pragma unroll
        for (int m = 0; m < 2; ++m)
            #pragma unroll
            for (int n = 0; n < 6; ++n) acc[m][n] = (f32x4){0.f, 0.f, 0.f, 0.f};

        #pragma unroll
        for (int kc = 0; kc < 4; ++kc) {
            short8 a0 = *(const short8*)&sX[wave * 32 + lr][kc * 32 + lk];
            short8 a1 = *(const short8*)&sX[wave * 32 + 16 + lr][kc * 32 + lk];
            #pragma unroll
            for (int n = 0; n < 6; ++n) {
                acc[0][n] = __builtin_amdgcn_mfma_f32_16x16x32_bf16(a0, bfr[n][kc], acc[0][n], 0, 0, 0);
                acc[1][n] = __builtin_amdgcn_mfma_f32_16x16x32_bf16(a1, bfr[n][kc], acc[1][n], 0, 0, 0);
            }
        }

        #pragma unroll
        for (int m = 0; m < 2; ++m) {
            #pragma unroll
            for (int r = 0; r < 4; ++r) {
                int t = t0 + wave * 32 + m * 16 + (lane >> 4) * 4 + r;
                unsigned short* dst = &xz[((size_t)b * T_ + t) * TU + lr];
                #pragma unroll
                for (int n = 0; n < 6; ++n)
                    dst[n * 16] = f2bf_rne(acc[m][n][r] + bi[n]);
            }
        }
    }
}

// ============================================================================
// Kernel 2: recurrence rec10. 256 blocks x 64 threads (1 wave/CU — measured
// optimum). The h@RK matvec now runs on the MATRIX pipe:
//   - h broadcast: 1 packed (h_hi|h_lo) u32 per lane, 8 static ds_bpermute
//     -> each lane holds its 8-element k-slice (replaces 32 readlanes)
//   - 18 mfma_f32_16x16x32_bf16: 6 col-groups x 3 precision terms
//     (h_hi*W_hi + h_lo*W_hi + h_hi*W_lo; W pre-scaled by -L2E / +2L2E and
//     hi/lo-split in 48 preloaded VGPRs) -> ~2^-17 matvec precision
//   - D: col = lane&15, rows replicated -> recA = acc[lane>>4] (3 cndmask),
//     recB = acc[4|5] (1 cndmask)
// Replaces the 32-readlane + 32-pkFMA + add-tree chain (~130 issue cycles +
// 4-deep latency chains) that two reschedule attempts (r4, r5) failed to fix.
// ============================================================================
__global__ __attribute__((amdgpu_flat_work_group_size(64, 64),
                          amdgpu_waves_per_eu(1, 1)))
void gru_rec10_kernel(
    const unsigned short* __restrict__ xz,
    const float* __restrict__ demo,
    const int*   __restrict__ lengths,
    const float* __restrict__ W1,
    const float* __restrict__ b1,
    const float* __restrict__ W2,
    const float* __restrict__ b2,
    const float* __restrict__ rec_kernel,
    const float* __restrict__ bias,
    const float* __restrict__ Wo,
    const float* __restrict__ bo,
    float* __restrict__ out)
{
    const int b   = blockIdx.x;
    const int l   = threadIdx.x;
    const int lc  = l & 31;
    const int len = lengths[b];
    const bool lower = (l < 32);

    const int kbase = (l >> 4) * 8;      // k-slice base for this lane
    const int cb    = l & 15;            // MFMA col within group

    // ---- preload B-fragments: RK columns, scaled, bf16 hi/lo split ----
    short8 Bhi[6], Blo[6];
    #pragma unroll
    for (int n = 0; n < 6; ++n) {
        const float scale = (n < 4) ? -L2E : 2.f * L2E;
        frag_u fh, fl;
        #pragma unroll
        for (int j2 = 0; j2 < 4; ++j2) {
            float w0 = scale * rec_kernel[(kbase + 2 * j2)     * TU + 16 * n + cb];
            float w1 = scale * rec_kernel[(kbase + 2 * j2 + 1) * TU + 16 * n + cb];
            unsigned hbits = pk_bf16(w0, w1);
            float r0 = w0 - bf2f((unsigned short)(hbits & 0xFFFFu));
            float r1 = w1 - bf2f((unsigned short)(hbits >> 16));
            fh.u[j2] = hbits;
            fl.u[j2] = pk_bf16(r0, r1);
        }
        Bhi[n] = fh.v; Blo[n] = fl.v;
    }
    float rbA = -L2E * bias[TU + l];
    float rbB = 2.f * L2E * bias[TU + 64 + lc];

    // bpermute byte addresses for h-slice gather (static)
    int ad[8];
    #pragma unroll
    for (int j = 0; j < 8; ++j) ad[j] = (kbase + j) * 4;

    // byte-select patterns: low halves (hi parts) / high halves (lo parts)
    unsigned selLO = 0x05040100u, selHI = 0x07060302u;
    asm volatile("" : "+v"(selLO), "+v"(selHI));

    // selection predicates (loop-invariant)
    const bool g1 = ((l >> 4) & 1) != 0;
    const bool g2 = ((l >> 4) & 2) != 0;
    const bool gB = (l & 16) != 0;

    // h0 = relu(demo@W1+b1)@W2+b2
    float av = 0.f;
    if (l < U_) {
        float a = b1[l];
        #pragma unroll
        for (int d = 0; d < D_; ++d) a += demo[b * D_ + d] * W1[d * U_ + l];
        av = fmaxf(a, 0.f);
    }
    float hv = b2[lc];
    #pragma unroll
    for (int k = 0; k < U_; ++k) hv += rdlane(av, k) * W2[k * U_ + lc];

    const unsigned short* xp = xz + (size_t)b * T_ * TU;
    unsigned short rA[4], rB[4];

    auto issue4 = [&](int tg) {
        #pragma unroll
        for (int i = 0; i < 4; ++i) {
            int t = tg + i; t = (t < len) ? t : (len - 1);
            rA[i] = xp[(size_t)t * TU + l];        // x_z (l<32) | x_r (l>=32)
            rB[i] = xp[(size_t)t * TU + 64 + lc];  // x_h
        }
    };

    // xApre = -L2E*xA + rbA ; xBpre = 2L2E*xB   (precomputed by caller)
    auto step = [&](float xApre, float xBpre) {
        // split h into bf16 hi + residual, pack, broadcast k-slices
        float hhi = __uint_as_float(__float_as_uint(hv) & 0xFFFF0000u);
        float hlo = hv - hhi;
        unsigned pk = pk_bf16(hhi, hlo);        // low16 = h_hi, high16 = h_lo
        int p[8];
        #pragma unroll
        for (int j = 0; j < 8; ++j)
            p[j] = __builtin_amdgcn_ds_bpermute(ad[j], (int)pk);

        // zero accs (independent -> fills bpermute latency)
        f32x4 acc[6];
        #pragma unroll
        for (int n = 0; n < 6; ++n) acc[n] = (f32x4){0.f, 0.f, 0.f, 0.f};

        // build A fragments (hi / lo) from packed pairs
        frag_u fa, fb;
        #pragma unroll
        for (int j2 = 0; j2 < 4; ++j2) {
            fa.u[j2] = perm_b32((unsigned)p[2 * j2 + 1], (unsigned)p[2 * j2], selLO);
            fb.u[j2] = perm_b32((unsigned)p[2 * j2 + 1], (unsigned)p[2 * j2], selHI);
        }
        short8 Ahi = fa.v, Alo = fb.v;

        // 18 MFMAs: 6 col-groups x (hi*Whi + lo*Whi + hi*Wlo)
        #pragma unroll
        for (int n = 0; n < 6; ++n) {
            acc[n] = __builtin_amdgcn_mfma_f32_16x16x32_bf16(Ahi, Bhi[n], acc[n], 0, 0, 0);
            acc[n] = __builtin_amdgcn_mfma_f32_16x16x32_bf16(Alo, Bhi[n], acc[n], 0, 0, 0);
            acc[n] = __builtin_amdgcn_mfma_f32_16x16x32_bf16(Ahi, Blo[n], acc[n], 0, 0, 0);
        }

        // select this lane's columns
        float a01 = g1 ? acc[1][0] : acc[0][0];
        float a23 = g1 ? acc[3][0] : acc[2][0];
        float dotA = g2 ? a23 : a01;
        float dotB = gB ? acc[5][0] : acc[4][0];

        float recA = dotA + xApre;
        float eA = fast_exp2(recA);
        float zr = fast_rcp(1.f + eA);       // z (l<32) | r (l>=32)
        float recB = dotB + rbB;
        float sw = swap_half(zr);            // partner's value
        float z  = lower ? zr : sw;
        float r  = lower ? sw : zr;
        float u2 = fmaf(r, recB, xBpre);     // 2L2E*(xB + r*rec_h)
        float e2 = fast_exp2(u2);
        float hh = fmaf(-2.f, fast_rcp(e2 + 1.f), 1.f);  // tanh
        hv = fmaf(z, hv - hh, hh);
    };

    issue4(0);
    const int full = len & ~3;
    for (int tg = 0; tg < full; tg += 4) {
        float pA0 = fmaf(bf2f(rA[0]), -L2E, rbA), pB0 = bf2f(rB[0]) * (2.f * L2E);
        float pA1 = fmaf(bf2f(rA[1]), -L2E, rbA), pB1 = bf2f(rB[1]) * (2.f * L2E);
        float pA2 = fmaf(bf2f(rA[2]), -L2E, rbA), pB2 = bf2f(rB[2]) * (2.f * L2E);
        float pA3 = fmaf(bf2f(rA[3]), -L2E, rbA), pB3 = bf2f(rB[3]) * (2.f * L2E);
        issue4(tg + 4);                        // prefetch next group
        step(pA0, pB0); step(pA1, pB1); step(pA2, pB2); step(pA3, pB3);
    }
    const int rem = len - full;
    if (rem > 0) step(fmaf(bf2f(rA[0]), -L2E, rbA), bf2f(rB[0]) * (2.f * L2E));
    if (rem > 1) step(fmaf(bf2f(rA[1]), -L2E, rbA), bf2f(rB[1]) * (2.f * L2E));
    if (rem > 2) step(fmaf(bf2f(rA[2]), -L2E, rbA), bf2f(rB[2]) * (2.f * L2E));

    float v = (l < U_) ? hv * Wo[l] : 0.f;
    v += __shfl_xor(v, 16);
    v += __shfl_xor(v, 8);
    v += __shfl_xor(v, 4);
    v += __shfl_xor(v, 2);
    v += __shfl_xor(v, 1);
    if (l == 0) out[b] = sigmoid_fast(v + bo[0]);
}

extern "C" void kernel_launch(void* const* d_in, const int* in_sizes, int n_in,
                              void* d_out, int out_size, void* d_ws, size_t ws_size,
                              hipStream_t stream) {
    const float* demo       = (const float*)d_in[0];
    const float* dt         = (const float*)d_in[1];
    const float* values     = (const float*)d_in[2];
    const int*   meas       = (const int*)  d_in[3];
    const int*   lengths    = (const int*)  d_in[4];
    const float* W1         = (const float*)d_in[5];
    const float* b1         = (const float*)d_in[6];
    const float* W2         = (const float*)d_in[7];
    const float* b2         = (const float*)d_in[8];
    const float* kern       = (const float*)d_in[9];
    const float* rec_kernel = (const float*)d_in[10];
    const float* bias       = (const float*)d_in[11];
    const float* Wo         = (const float*)d_in[12];
    const float* bo         = (const float*)d_in[13];
    float* out = (float*)d_out;

    unsigned short* xz = (unsigned short*)d_ws;   // 100.7 MB, fits (validated)
    hipLaunchKernelGGL(gru_xz4_kernel, dim3(B_ * (T_ / MTILE) / TPB), dim3(256), 0, stream,
                       dt, values, meas, kern, bias, lengths, xz);
    hipLaunchKernelGGL(gru_rec10_kernel, dim3(B_), dim3(64), 0, stream,
                       xz, demo, lengths, W1, b1, W2, b2,
                       rec_kernel, bias, Wo, bo, out);
}

// Round 7
// 579.692 us; speedup vs baseline: 1.4777x; 1.4777x over previous
//
#include <hip/hip_runtime.h>

#define B_    256
#define T_    2048
#define F_    37
#define TF    111   // 3F
#define U_    32
#define TU    96    // 3U
#define D_    16

#define KP    128   // padded K for MFMA
#define XSTR  136   // LDS row stride in bf16 (272 B)
#define MTILE 128   // timesteps per tile
#define TPB   4     // tiles per block (xz kernel)

#define L2E 1.4426950408889634f

typedef __attribute__((ext_vector_type(8))) short short8;
typedef __attribute__((ext_vector_type(4))) float f32x4;
typedef __attribute__((ext_vector_type(2))) float f32x2;

__device__ __forceinline__ float fast_exp2(float x) {
    float r; asm("v_exp_f32 %0, %1" : "=v"(r) : "v"(x)); return r;
}
__device__ __forceinline__ float fast_rcp(float x) {
    float r; asm("v_rcp_f32 %0, %1" : "=v"(r) : "v"(x)); return r;
}
__device__ __forceinline__ float sigmoid_fast(float x) {
    return fast_rcp(1.f + fast_exp2(-L2E * x));
}
__device__ __forceinline__ float rdlane(float v, int k) {
    return __uint_as_float(__builtin_amdgcn_readlane(__float_as_uint(v), k));
}
__device__ __forceinline__ float bf2f(unsigned short u) {
    return __uint_as_float(((unsigned)u) << 16);
}
__device__ __forceinline__ unsigned short f2bf_rne(float x) {
    unsigned u = __float_as_uint(x);
    return (unsigned short)((u + 0x7FFFu + ((u >> 16) & 1u)) >> 16);
}
__device__ __forceinline__ unsigned pk_bf16(float a, float b) {
    unsigned u;
    asm("v_cvt_pk_bf16_f32 %0, %1, %2" : "=v"(u) : "v"(a), "v"(b));
    return u;
}

// packed f32 math: d = (s0.lo*s1.lo[+d.lo], s0.hi*s1.hi[+d.hi])
#define PKMUL(d, hs, w) \
    asm("v_pk_mul_f32 %0, %1, %2" : "=v"(d) : "s"(hs), "v"(w))
#define PKFMA(d, hs, w) \
    asm("v_pk_fma_f32 %0, %1, %2, %0" : "+v"(d) : "s"(hs), "v"(w))
#define PKADD(d, a, b) \
    asm("v_pk_add_f32 %0, %1, %2" : "=v"(d) : "v"(a), "v"(b))

#define SCHED_FENCE() __builtin_amdgcn_sched_barrier(0)

// ============================================================================
// Kernel 1: xz[b][t][0:96] = x[b,t,:] @ K + b_in (bf16 out), via MFMA.
// Tiles with t0 >= lengths[b] are skipped (validated rounds 2-5).
// ============================================================================
__global__ __launch_bounds__(256, 2) void gru_xz4_kernel(
    const float* __restrict__ dt,
    const float* __restrict__ values,
    const int*   __restrict__ meas,
    const float* __restrict__ kern,
    const float* __restrict__ bias,
    const int*   __restrict__ lengths,
    unsigned short* __restrict__ xz)
{
    __shared__ unsigned short sX[MTILE][XSTR];   // 34816 B
    __shared__ unsigned short sKT[TU][XSTR];     // 26112 B

    const int tid  = threadIdx.x;
    const int wave = tid >> 6;
    const int lane = tid & 63;
    const int lr   = lane & 15;          // A-row / B-col / D-col
    const int lk   = (lane >> 4) * 8;    // k offset within frag

    for (int idx = tid; idx < TU * (KP / 2); idx += 256) {
        int j = idx >> 6, kp = idx & 63;
        int k0 = 2 * kp, k1 = k0 + 1;
        float v0 = (k0 < TF) ? kern[k0 * TU + j] : 0.f;
        float v1 = (k1 < TF) ? kern[k1 * TU + j] : 0.f;
        *(unsigned*)&sKT[j][2 * kp] = pk_bf16(v0, v1);
    }
    __syncthreads();

    float bi[6];
    #pragma unroll
    for (int n = 0; n < 6; ++n) bi[n] = bias[n * 16 + lr];
    short8 bfr[6][4];
    #pragma unroll
    for (int n = 0; n < 6; ++n)
        #pragma unroll
        for (int kc = 0; kc < 4; ++kc)
            bfr[n][kc] = *(const short8*)&sKT[n * 16 + lr][kc * 32 + lk];

    for (int tt = 0; tt < TPB; ++tt) {
        const int tile = blockIdx.x * TPB + tt;
        const int b    = tile >> 4;
        const int t0   = (tile & 15) * MTILE;

        // uniform per block-iteration: all threads take the same path, so the
        // barrier pairing below stays consistent.
        if (t0 >= lengths[b]) continue;

        __syncthreads();

        for (int i = tid; i < MTILE * F_; i += 256) {
            int t = i / F_, f = i - t * F_;
            size_t g = ((size_t)b * T_ + (t0 + t)) * F_ + f;
            sX[t][f] = f2bf_rne(values[g]);
        }
        for (int i = tid; i < MTILE * F_; i += 256) {
            int t = i / F_, f = i - t * F_;
            size_t g = ((size_t)b * T_ + (t0 + t)) * F_ + f;
            sX[t][F_ + f] = meas[g] ? (unsigned short)0x3F80 : (unsigned short)0;
        }
        for (int i = tid; i < MTILE * F_; i += 256) {
            int t = i / F_, f = i - t * F_;
            size_t g = ((size_t)b * T_ + (t0 + t)) * F_ + f;
            sX[t][2 * F_ + f] = f2bf_rne(dt[g]);
        }
        for (int i = tid; i < MTILE * (KP - TF); i += 256) {
            int t = i / (KP - TF), p = i - t * (KP - TF);
            sX[t][TF + p] = 0;
        }
        __syncthreads();

        f32x4 acc[2][6];
        #pragma unroll
        for (int m = 0; m < 2; ++m)
            #pragma unroll
            for (int n = 0; n < 6; ++n) acc[m][n] = (f32x4){0.f, 0.f, 0.f, 0.f};

        #pragma unroll
        for (int kc = 0; kc < 4; ++kc) {
            short8 a0 = *(const short8*)&sX[wave * 32 + lr][kc * 32 + lk];
            short8 a1 = *(const short8*)&sX[wave * 32 + 16 + lr][kc * 32 + lk];
            #pragma unroll
            for (int n = 0; n < 6; ++n) {
                acc[0][n] = __builtin_amdgcn_mfma_f32_16x16x32_bf16(a0, bfr[n][kc], acc[0][n], 0, 0, 0);
                acc[1][n] = __builtin_amdgcn_mfma_f32_16x16x32_bf16(a1, bfr[n][kc], acc[1][n], 0, 0, 0);
            }
        }

        #pragma unroll
        for (int m = 0; m < 2; ++m) {
            #pragma unroll
            for (int r = 0; r < 4; ++r) {
                int t = t0 + wave * 32 + m * 16 + (lane >> 4) * 4 + r;
                unsigned short* dst = &xz[((size_t)b * T_ + t) * TU + lr];
                #pragma unroll
                for (int n = 0; n < 6; ++n)
                    dst[n * 16] = f2bf_rne(acc[m][n][r] + bi[n]);
            }
        }
    }
}

// ============================================================================
// Kernel 2: recurrence rec11. 256 blocks x 64 threads (1 wave/CU — measured
// optimum r2/r3; MFMA-on-1-wave regressed r6). rec9 structure with a
// SHORTENED critical tail:
//   zq = fma(z, h-1, 1), m2q = fma(2,z,-2)  ->  hv = fma(m2q, R, zq)
//     (1 hop after the tanh rcp instead of 3: hh/sub folded away)
//   u2_low = fma(s, recB, zrB), zrB = fma(-zr, recB, xBpre)
//     (swapped-r product expanded; sw subtract off the critical path)
//   B-matvec moved between eA and zr so recB is ready early (its issue
//     fills the exp latency; zrB is now on the critical path).
// Tail zr->hv: 11 hops -> 7 (perm, s, u2, exp, add, rcp, hv).
// ============================================================================
__global__ __attribute__((amdgpu_flat_work_group_size(64, 64),
                          amdgpu_waves_per_eu(1, 1)))
void gru_rec11_kernel(
    const unsigned short* __restrict__ xz,
    const float* __restrict__ demo,
    const int*   __restrict__ lengths,
    const float* __restrict__ W1,
    const float* __restrict__ b1,
    const float* __restrict__ W2,
    const float* __restrict__ b2,
    const float* __restrict__ rec_kernel,
    const float* __restrict__ bias,
    const float* __restrict__ Wo,
    const float* __restrict__ bo,
    float* __restrict__ out)
{
    const int b   = blockIdx.x;
    const int l   = threadIdx.x;
    const int lc  = l & 31;
    const int len = lengths[b];
    const bool lower = (l < 32);

    // wpA[m] = -L2E * (RK[2m][l],    RK[2m+1][l])      (z col l<32 | r col)
    // wpB[m] = 2L2E * (RK[2m][64+lc],RK[2m+1][64+lc])  (h col)
    f32x2 wpA[16], wpB[16];
    #pragma unroll
    for (int m = 0; m < 16; ++m) {
        wpA[m] = (f32x2){-L2E * rec_kernel[(2 * m) * TU + l],
                         -L2E * rec_kernel[(2 * m + 1) * TU + l]};
        wpB[m] = (f32x2){2.f * L2E * rec_kernel[(2 * m) * TU + 64 + lc],
                         2.f * L2E * rec_kernel[(2 * m + 1) * TU + 64 + lc]};
    }
    float rbA = -L2E * bias[TU + l];
    float rbB = 2.f * L2E * bias[TU + 64 + lc];
    #pragma unroll
    for (int m = 0; m < 16; ++m) {
        asm volatile("" : "+v"(wpA[m]));
        asm volatile("" : "+v"(wpB[m]));
    }
    asm volatile("" : "+v"(rbA), "+v"(rbB));

    // h0 = relu(demo@W1+b1)@W2+b2
    float av = 0.f;
    if (l < U_) {
        float a = b1[l];
        #pragma unroll
        for (int d = 0; d < D_; ++d) a += demo[b * D_ + d] * W1[d * U_ + l];
        av = fmaxf(a, 0.f);
    }
    float hv = b2[lc];
    #pragma unroll
    for (int k = 0; k < U_; ++k) hv += rdlane(av, k) * W2[k * U_ + lc];
    float hm1 = hv - 1.f;

    const unsigned short* xp = xz + (size_t)b * T_ * TU;
    unsigned short rA[4], rB[4];

    auto issue4 = [&](int tg) {
        #pragma unroll
        for (int i = 0; i < 4; ++i) {
            int t = tg + i; t = (t < len) ? t : (len - 1);
            rA[i] = xp[(size_t)t * TU + l];        // x_z (l<32) | x_r (l>=32)
            rB[i] = xp[(size_t)t * TU + 64 + lc];  // x_h
        }
    };

    // xApre = -L2E*xA + rbA ; xBpre = 2L2E*xB   (precomputed by caller)
    auto step = [&](float xApre, float xBpre) {
        // R1: broadcast h into 16 SGPR pairs, all up front
        f32x2 hs[16];
        #pragma unroll
        for (int m = 0; m < 16; ++m)
            hs[m] = (f32x2){rdlane(hv, 2 * m), rdlane(hv, 2 * m + 1)};
        SCHED_FENCE();
        // R2: A-path matvec -> recA -> exp
        f32x2 aA0 = (f32x2){xApre, 0.f}, aA1, aA2, aA3;
        PKFMA(aA0, hs[0], wpA[0]);
        PKMUL(aA1, hs[1], wpA[1]);
        PKMUL(aA2, hs[2], wpA[2]);
        PKMUL(aA3, hs[3], wpA[3]);
        #pragma unroll
        for (int g = 1; g < 4; ++g) {
            PKFMA(aA0, hs[4 * g],     wpA[4 * g]);
            PKFMA(aA1, hs[4 * g + 1], wpA[4 * g + 1]);
            PKFMA(aA2, hs[4 * g + 2], wpA[4 * g + 2]);
            PKFMA(aA3, hs[4 * g + 3], wpA[4 * g + 3]);
        }
        f32x2 tA01, tA23, tA;
        PKADD(tA01, aA0, aA1); PKADD(tA23, aA2, aA3); PKADD(tA, tA01, tA23);
        float recA = tA.x + tA.y;
        float eA = fast_exp2(recA);
        SCHED_FENCE();
        // R3: FULL B-path matvec + tree — issue fills exp latency; recB early
        f32x2 aB0 = (f32x2){rbB, 0.f}, aB1, aB2, aB3;
        PKFMA(aB0, hs[0], wpB[0]);
        PKMUL(aB1, hs[1], wpB[1]);
        PKMUL(aB2, hs[2], wpB[2]);
        PKMUL(aB3, hs[3], wpB[3]);
        #pragma unroll
        for (int g = 1; g < 4; ++g) {
            PKFMA(aB0, hs[4 * g],     wpB[4 * g]);
            PKFMA(aB1, hs[4 * g + 1], wpB[4 * g + 1]);
            PKFMA(aB2, hs[4 * g + 2], wpB[4 * g + 2]);
            PKFMA(aB3, hs[4 * g + 3], wpB[4 * g + 3]);
        }
        f32x2 tB01, tB23, tB;
        PKADD(tB01, aB0, aB1); PKADD(tB23, aB2, aB3); PKADD(tB, tB01, tB23);
        float recB = tB.x + tB.y;
        SCHED_FENCE();
        // R4: zr then tail. Critical: zr->perm->s->u2->exp->add->rcp->hv.
        float zr = fast_rcp(1.f + eA);       // z (l<32) | r (l>=32)
        unsigned zri = __float_as_uint(zr);
        auto p = __builtin_amdgcn_permlane32_swap(zri, zri, false, false);
        // fill perm latency: off-path prep
        float zrB   = fmaf(-zr, recB, xBpre);   // xBpre - zr*recB
        float u2_up = fmaf(zr, recB, xBpre);    // upper lanes: r = own zr
        float zq_l  = fmaf(zr, hm1, 1.f);       // lower lanes: z = own zr
        float m2q_l = fmaf(2.f, zr, -2.f);
        float s = __uint_as_float(p[0]) + __uint_as_float(p[1]); // own+partner
        float u2_lo = fmaf(s, recB, zrB);       // (s-zr)*recB + xBpre
        float u2 = lower ? u2_lo : u2_up;
        float e2 = fast_exp2(u2);
        // fill exp latency: upper-lane z prep
        float sw    = s - zr;                   // partner's value
        float zq_u  = fmaf(sw, hm1, 1.f);
        float m2q_u = fmaf(2.f, sw, -2.f);
        float zq  = lower ? zq_l : zq_u;
        float m2q = lower ? m2q_l : m2q_u;
        float R = fast_rcp(e2 + 1.f);
        hv  = fmaf(m2q, R, zq);                 // z*h + (1-z)*(1-2R)
        hm1 = hv - 1.f;                         // off-path, for next step
    };

    issue4(0);
    const int full = len & ~3;
    for (int tg = 0; tg < full; tg += 4) {
        float pA0 = fmaf(bf2f(rA[0]), -L2E, rbA), pB0 = bf2f(rB[0]) * (2.f * L2E);
        float pA1 = fmaf(bf2f(rA[1]), -L2E, rbA), pB1 = bf2f(rB[1]) * (2.f * L2E);
        float pA2 = fmaf(bf2f(rA[2]), -L2E, rbA), pB2 = bf2f(rB[2]) * (2.f * L2E);
        float pA3 = fmaf(bf2f(rA[3]), -L2E, rbA), pB3 = bf2f(rB[3]) * (2.f * L2E);
        issue4(tg + 4);                        // prefetch next group
        step(pA0, pB0); step(pA1, pB1); step(pA2, pB2); step(pA3, pB3);
    }
    const int rem = len - full;
    if (rem > 0) step(fmaf(bf2f(rA[0]), -L2E, rbA), bf2f(rB[0]) * (2.f * L2E));
    if (rem > 1) step(fmaf(bf2f(rA[1]), -L2E, rbA), bf2f(rB[1]) * (2.f * L2E));
    if (rem > 2) step(fmaf(bf2f(rA[2]), -L2E, rbA), bf2f(rB[2]) * (2.f * L2E));

    float v = (l < U_) ? hv * Wo[l] : 0.f;
    v += __shfl_xor(v, 16);
    v += __shfl_xor(v, 8);
    v += __shfl_xor(v, 4);
    v += __shfl_xor(v, 2);
    v += __shfl_xor(v, 1);
    if (l == 0) out[b] = sigmoid_fast(v + bo[0]);
}

extern "C" void kernel_launch(void* const* d_in, const int* in_sizes, int n_in,
                              void* d_out, int out_size, void* d_ws, size_t ws_size,
                              hipStream_t stream) {
    const float* demo       = (const float*)d_in[0];
    const float* dt         = (const float*)d_in[1];
    const float* values     = (const float*)d_in[2];
    const int*   meas       = (const int*)  d_in[3];
    const int*   lengths    = (const int*)  d_in[4];
    const float* W1         = (const float*)d_in[5];
    const float* b1         = (const float*)d_in[6];
    const float* W2         = (const float*)d_in[7];
    const float* b2         = (const float*)d_in[8];
    const float* kern       = (const float*)d_in[9];
    const float* rec_kernel = (const float*)d_in[10];
    const float* bias       = (const float*)d_in[11];
    const float* Wo         = (const float*)d_in[12];
    const float* bo         = (const float*)d_in[13];
    float* out = (float*)d_out;

    unsigned short* xz = (unsigned short*)d_ws;   // 100.7 MB, fits (validated)
    hipLaunchKernelGGL(gru_xz4_kernel, dim3(B_ * (T_ / MTILE) / TPB), dim3(256), 0, stream,
                       dt, values, meas, kern, bias, lengths, xz);
    hipLaunchKernelGGL(gru_rec11_kernel, dim3(B_), dim3(64), 0, stream,
                       xz, demo, lengths, W1, b1, W2, b2,
                       rec_kernel, bias, Wo, bo, out);
}